// Round 10
// baseline (170.003 us; speedup 1.0000x reference)
//
#include <hip/hip_runtime.h>

#define BATCH 2048
#define DIM   256
#define WAVES 8   // 512 threads/block

typedef _Float16 half8 __attribute__((ext_vector_type(8)));  // 8 x f16 (4 VGPR)
typedef _Float16 half4 __attribute__((ext_vector_type(4)));
typedef __attribute__((ext_vector_type(4))) float f32x4;

// Packed-weight tile table (layers 1..5), f16 hi-only:
// (FI,FO): (32,64) (64,128) (128,64) (64,32) (32,16)
// KT=FI/32, NT=FO/16, tiles=KT*NT: 4, 16, 16, 4, 1 -> bases 0,4,20,36,40
#define NTILES 41
#define TILE_HALVES 512   // 64 lanes * 8 f16 = 1 KB per tile

// ---- one MFMA layer for RT=4 row-tiles (M=64) owned by one wave ----
// A = f16 activations (hi only), B = f16 weights (hi only) -> 1 MFMA/tile/rt.
template <int FI, int FO, int LBASE, bool EXTRACT>
__device__ __forceinline__ void layer_mfma(
    const _Float16* __restrict__ packs,   // LDS: 41 tiles * 512 halves
    const float* __restrict__ bld,
    int m, int q, int lane, _Float16* __restrict__ bw,  // LDS [4][16*36]
    const half8 (*A)[4], half8 (*O)[4]) {
  constexpr int KT = FI / 32, NT = FO / 16;
#pragma unroll
  for (int nt = 0; nt < NT; ++nt) {
    const float bias = bld[nt * 16 + m];
    f32x4 acc[4];
#pragma unroll
    for (int rt = 0; rt < 4; ++rt) acc[rt] = {bias, bias, bias, bias};
#pragma unroll
    for (int kt = 0; kt < KT; ++kt) {
      const _Float16* tb = packs + (size_t)(LBASE + nt * KT + kt) * TILE_HALVES;
      const half8 Bh = *(const half8*)(tb + lane * 8);
#pragma unroll
      for (int rt = 0; rt < 4; ++rt)
        acc[rt] = __builtin_amdgcn_mfma_f32_16x16x32_f16(A[rt][kt], Bh, acc[rt], 0, 0, 0);
    }
    const int hcol = (nt & 1) * 16 + m;
#pragma unroll
    for (int rt = 0; rt < 4; ++rt)
#pragma unroll
      for (int r = 0; r < 4; ++r)
        bw[rt * 576 + (q * 4 + r) * 36 + hcol] =
            (_Float16)fmaxf(acc[rt][r], 0.0f);  // ReLU + cvt on write
    if (EXTRACT && (nt & 1)) {  // 32-col pair complete -> next A-frag ktn
      const int ktn = nt >> 1;
#pragma unroll
      for (int rt = 0; rt < 4; ++rt) {
        const _Float16* p = &bw[rt * 576 + m * 36 + q * 8];  // 8-B aligned
        const half4 v0 = *(const half4*)p;
        const half4 v1 = *(const half4*)(p + 4);
        half8 o;
#pragma unroll
        for (int j = 0; j < 4; ++j) { o[j] = v0[j]; o[4 + j] = v1[j]; }
        O[rt][ktn] = o;
      }
    }
  }
}

// ---- fused kernel: grid (256 d, 2 batch-halves). Phase 1: pack W[d] into
// LDS (f16 hi, B-frag order). Phase 2: 2 iterations (8 waves x 64 rows).
// LDS total 78848 B -> 2 blocks/CU, 4 waves/SIMD.
__global__ __launch_bounds__(512, 4) void mlp_fused(
    const float* __restrict__ x,
    const float* __restrict__ W0, const float* __restrict__ b0,
    const float* __restrict__ W1, const float* __restrict__ b1,
    const float* __restrict__ W2, const float* __restrict__ b2,
    const float* __restrict__ W3, const float* __restrict__ b3,
    const float* __restrict__ W4, const float* __restrict__ b4,
    const float* __restrict__ W5, const float* __restrict__ b5,
    const float* __restrict__ W6, const float* __restrict__ b6,
    float* __restrict__ partial) {
  const int t = threadIdx.x;
  const int lane = t & 63;
  const int wave = t >> 6;
  const int m = lane & 15, q = lane >> 4;
  const int d = blockIdx.x;
  const int half = blockIdx.y;   // which 1024 rows

  __shared__ __align__(16) _Float16 packs[NTILES * TILE_HALVES];  // 41 KB
  __shared__ __align__(16) _Float16 act[WAVES][4 * 576];          // 36 KB

  // ---- phase 1: gather W1..W5[d] into LDS pack (frag order, f16 hi) ----
  for (int job = t; job < NTILES * 64; job += 512) {
    const int tile = job >> 6, jl = job & 63;
    const int jm = jl & 15, jq = jl >> 4;
    const float* W; int FI, FO, lt;
    if (tile < 4)       { W = W1; FI = 32;  FO = 64;  lt = tile; }
    else if (tile < 20) { W = W2; FI = 64;  FO = 128; lt = tile - 4; }
    else if (tile < 36) { W = W3; FI = 128; FO = 64;  lt = tile - 20; }
    else if (tile < 40) { W = W4; FI = 64;  FO = 32;  lt = tile - 36; }
    else                { W = W5; FI = 32;  FO = 16;  lt = 0; }
    const int KT = FI >> 5;
    const int nt = lt / KT, kt = lt - nt * KT;   // matches layer_mfma order
    const float* Wp = W + (size_t)d * FI * FO +
                      (size_t)(kt * 32 + jq * 8) * FO + nt * 16 + jm;
    half8 hi;
#pragma unroll
    for (int j = 0; j < 8; ++j) hi[j] = (_Float16)Wp[(size_t)j * FO];
    *(half8*)(packs + (size_t)tile * TILE_HALVES + jl * 8) = hi;
  }

  // Hoist wave-uniform L0/L6 params while the pack settles.
  float w0r[8], b0r[8];
#pragma unroll
  for (int j = 0; j < 8; ++j) {
    w0r[j] = W0[d * 32 + q * 8 + j];
    b0r[j] = b0[d * 32 + q * 8 + j];
  }
  const float w6 = W6[d * 16 + m];
  const float bias6 = b6[d];

  __syncthreads();   // pack ready; the ONLY barrier

  _Float16* bw = act[wave];
  half8 A0[4][4], A1[4][4];

  // ---- phase 2: 2 iterations x (8 waves * 64 rows) = 1024 rows ----
  for (int it = 0; it < 2; ++it) {
    const int row0 = half * 1024 + it * 512 + wave * 64;

    // L0: 1 -> 32 in VALU -> L1 A-frags.
#pragma unroll
    for (int rt = 0; rt < 4; ++rt) {
      const float xv = x[(size_t)(row0 + rt * 16 + m) * DIM + d];
      half8 h;
#pragma unroll
      for (int j = 0; j < 8; ++j)
        h[j] = (_Float16)fmaxf(fmaf(xv, w0r[j], b0r[j]), 0.0f);
      A0[rt][0] = h;
    }

    layer_mfma<32, 64, 0, true>(packs, b1 + d * 64, m, q, lane, bw, A0, A1);
    layer_mfma<64, 128, 4, true>(packs, b2 + d * 128, m, q, lane, bw, A1, A0);
    layer_mfma<128, 64, 20, true>(packs, b3 + d * 64, m, q, lane, bw, A0, A1);
    layer_mfma<64, 32, 36, true>(packs, b4 + d * 32, m, q, lane, bw, A1, A0);
    layer_mfma<32, 16, 40, false>(packs, b5 + d * 16, m, q, lane, bw, A0, A1);

    // L6: 16 -> 1 from LDS; shuffle-reduce 16 cols.
#pragma unroll
    for (int rt = 0; rt < 4; ++rt) {
#pragma unroll
      for (int r = 0; r < 4; ++r) {
        float v = (float)bw[rt * 576 + (q * 4 + r) * 36 + m] * w6;
        v += __shfl_xor(v, 1);
        v += __shfl_xor(v, 2);
        v += __shfl_xor(v, 4);
        v += __shfl_xor(v, 8);
        if (m == 0)
          partial[(size_t)d * BATCH + row0 + rt * 16 + q * 4 + r] = v + bias6;
      }
    }
  }
}

__global__ __launch_bounds__(256) void reduce_kernel(
    const float* __restrict__ partial, float* __restrict__ out) {
  const int b = blockIdx.x * blockDim.x + threadIdx.x;
  float s = 0.0f;
#pragma unroll 8
  for (int d = 0; d < DIM; ++d) s += partial[(size_t)d * BATCH + b];
  out[b] = s;
}

extern "C" void kernel_launch(void* const* d_in, const int* in_sizes, int n_in,
                              void* d_out, int out_size, void* d_ws, size_t ws_size,
                              hipStream_t stream) {
  const float* x = (const float*)d_in[0];
  const float* W[7];
  const float* B[7];
  for (int l = 0; l < 7; ++l) {
    W[l] = (const float*)d_in[1 + 2 * l];
    B[l] = (const float*)d_in[2 + 2 * l];
  }
  float* partial = (float*)d_ws;  // 2 MB

  mlp_fused<<<dim3(DIM, 2), dim3(512), 0, stream>>>(
      x, W[0], B[0], W[1], B[1], W[2], B[2], W[3], B[3], W[4], B[4], W[5], B[5],
      W[6], B[6], partial);

  reduce_kernel<<<dim3(BATCH / 256), dim3(256), 0, stream>>>(partial,
                                                             (float*)d_out);
}

// Round 11
// 155.075 us; speedup vs baseline: 1.0963x; 1.0963x over previous
//
#include <hip/hip_runtime.h>

#define BATCH 2048
#define DIM   256
#define WAVES 8   // 512 threads/block

typedef _Float16 half8 __attribute__((ext_vector_type(8)));  // 8 x f16 (4 VGPR)
typedef _Float16 half4 __attribute__((ext_vector_type(4)));
typedef __attribute__((ext_vector_type(4))) float f32x4;

// Packed-weight tile table (layers 1..5), f16 hi-only:
// (FI,FO): (32,64) (64,128) (128,64) (64,32) (32,16)
// KT=FI/32, NT=FO/16, tiles=KT*NT: 4, 16, 16, 4, 1 -> bases 0,4,20,36,40
#define NTILES 41
#define TILE_HALVES 512   // 64 lanes * 8 f16 = 1 KB per tile

// ---- one MFMA layer for RT=4 row-tiles (M=64) owned by one wave ----
// A = f16 activations (hi only), B = f16 weights (hi only) -> 1 MFMA/tile/rt.
template <int FI, int FO, int LBASE, bool EXTRACT>
__device__ __forceinline__ void layer_mfma(
    const _Float16* __restrict__ packs,   // LDS: 41 tiles * 512 halves
    const float* __restrict__ bld,
    int m, int q, int lane, _Float16* __restrict__ bw,  // LDS [4][16*36]
    const half8 (*A)[4], half8 (*O)[4]) {
  constexpr int KT = FI / 32, NT = FO / 16;
#pragma unroll
  for (int nt = 0; nt < NT; ++nt) {
    const float bias = bld[nt * 16 + m];
    f32x4 acc[4];
#pragma unroll
    for (int rt = 0; rt < 4; ++rt) acc[rt] = {bias, bias, bias, bias};
#pragma unroll
    for (int kt = 0; kt < KT; ++kt) {
      const _Float16* tb = packs + (size_t)(LBASE + nt * KT + kt) * TILE_HALVES;
      const half8 Bh = *(const half8*)(tb + lane * 8);
#pragma unroll
      for (int rt = 0; rt < 4; ++rt)
        acc[rt] = __builtin_amdgcn_mfma_f32_16x16x32_f16(A[rt][kt], Bh, acc[rt], 0, 0, 0);
    }
    const int hcol = (nt & 1) * 16 + m;
#pragma unroll
    for (int rt = 0; rt < 4; ++rt)
#pragma unroll
      for (int r = 0; r < 4; ++r)
        bw[rt * 576 + (q * 4 + r) * 36 + hcol] =
            (_Float16)fmaxf(acc[rt][r], 0.0f);  // ReLU + cvt on write
    if (EXTRACT && (nt & 1)) {  // 32-col pair complete -> next A-frag ktn
      const int ktn = nt >> 1;
#pragma unroll
      for (int rt = 0; rt < 4; ++rt) {
        const _Float16* p = &bw[rt * 576 + m * 36 + q * 8];  // 8-B aligned
        const half4 v0 = *(const half4*)p;
        const half4 v1 = *(const half4*)(p + 4);
        half8 o;
#pragma unroll
        for (int j = 0; j < 4; ++j) { o[j] = v0[j]; o[4 + j] = v1[j]; }
        O[rt][ktn] = o;
      }
    }
  }
}

// ---- fused kernel: grid (256 d, 2 batch-halves). Phase 1: pack W[d] into
// LDS (f16 hi, B-frag order). Phase 2: 2 iterations (8 waves x 64 rows).
// LDS total 78848 B -> 2 blocks/CU by LDS; launch_bounds(512,2) leaves the
// allocator free (~120 VGPR expected <= 128 -> HW reaches 16 waves/CU).
// NOTE R10: (512,4) forced a 64-VGPR allocation and ~190 MB of scratch spill.
__global__ __launch_bounds__(512, 2) void mlp_fused(
    const float* __restrict__ x,
    const float* __restrict__ W0, const float* __restrict__ b0,
    const float* __restrict__ W1, const float* __restrict__ b1,
    const float* __restrict__ W2, const float* __restrict__ b2,
    const float* __restrict__ W3, const float* __restrict__ b3,
    const float* __restrict__ W4, const float* __restrict__ b4,
    const float* __restrict__ W5, const float* __restrict__ b5,
    const float* __restrict__ W6, const float* __restrict__ b6,
    float* __restrict__ partial) {
  const int t = threadIdx.x;
  const int lane = t & 63;
  const int wave = t >> 6;
  const int m = lane & 15, q = lane >> 4;
  const int d = blockIdx.x;
  const int half = blockIdx.y;   // which 1024 rows

  __shared__ __align__(16) _Float16 packs[NTILES * TILE_HALVES];  // 41 KB
  __shared__ __align__(16) _Float16 act[WAVES][4 * 576];          // 36 KB

  // ---- phase 1: gather W1..W5[d] into LDS pack (frag order, f16 hi) ----
  for (int job = t; job < NTILES * 64; job += 512) {
    const int tile = job >> 6, jl = job & 63;
    const int jm = jl & 15, jq = jl >> 4;
    const float* W; int FI, FO, lt;
    if (tile < 4)       { W = W1; FI = 32;  FO = 64;  lt = tile; }
    else if (tile < 20) { W = W2; FI = 64;  FO = 128; lt = tile - 4; }
    else if (tile < 36) { W = W3; FI = 128; FO = 64;  lt = tile - 20; }
    else if (tile < 40) { W = W4; FI = 64;  FO = 32;  lt = tile - 36; }
    else                { W = W5; FI = 32;  FO = 16;  lt = 0; }
    const int KT = FI >> 5;
    const int nt = lt / KT, kt = lt - nt * KT;   // matches layer_mfma order
    const float* Wp = W + (size_t)d * FI * FO +
                      (size_t)(kt * 32 + jq * 8) * FO + nt * 16 + jm;
    half8 hi;
#pragma unroll
    for (int j = 0; j < 8; ++j) hi[j] = (_Float16)Wp[(size_t)j * FO];
    *(half8*)(packs + (size_t)tile * TILE_HALVES + jl * 8) = hi;
  }

  // Hoist wave-uniform L0/L6 params while the pack settles.
  float w0r[8], b0r[8];
#pragma unroll
  for (int j = 0; j < 8; ++j) {
    w0r[j] = W0[d * 32 + q * 8 + j];
    b0r[j] = b0[d * 32 + q * 8 + j];
  }
  const float w6 = W6[d * 16 + m];
  const float bias6 = b6[d];

  __syncthreads();   // pack ready; the ONLY barrier

  _Float16* bw = act[wave];
  half8 A0[4][4], A1[4][4];

  // ---- phase 2: 2 iterations x (8 waves * 64 rows) = 1024 rows ----
  for (int it = 0; it < 2; ++it) {
    const int row0 = half * 1024 + it * 512 + wave * 64;

    // L0: 1 -> 32 in VALU -> L1 A-frags.
#pragma unroll
    for (int rt = 0; rt < 4; ++rt) {
      const float xv = x[(size_t)(row0 + rt * 16 + m) * DIM + d];
      half8 h;
#pragma unroll
      for (int j = 0; j < 8; ++j)
        h[j] = (_Float16)fmaxf(fmaf(xv, w0r[j], b0r[j]), 0.0f);
      A0[rt][0] = h;
    }

    layer_mfma<32, 64, 0, true>(packs, b1 + d * 64, m, q, lane, bw, A0, A1);
    layer_mfma<64, 128, 4, true>(packs, b2 + d * 128, m, q, lane, bw, A1, A0);
    layer_mfma<128, 64, 20, true>(packs, b3 + d * 64, m, q, lane, bw, A0, A1);
    layer_mfma<64, 32, 36, true>(packs, b4 + d * 32, m, q, lane, bw, A1, A0);
    layer_mfma<32, 16, 40, false>(packs, b5 + d * 16, m, q, lane, bw, A0, A1);

    // L6: 16 -> 1 from LDS; shuffle-reduce 16 cols.
#pragma unroll
    for (int rt = 0; rt < 4; ++rt) {
#pragma unroll
      for (int r = 0; r < 4; ++r) {
        float v = (float)bw[rt * 576 + (q * 4 + r) * 36 + m] * w6;
        v += __shfl_xor(v, 1);
        v += __shfl_xor(v, 2);
        v += __shfl_xor(v, 4);
        v += __shfl_xor(v, 8);
        if (m == 0)
          partial[(size_t)d * BATCH + row0 + rt * 16 + q * 4 + r] = v + bias6;
      }
    }
  }
}

__global__ __launch_bounds__(256) void reduce_kernel(
    const float* __restrict__ partial, float* __restrict__ out) {
  const int b = blockIdx.x * blockDim.x + threadIdx.x;
  float s = 0.0f;
#pragma unroll 8
  for (int d = 0; d < DIM; ++d) s += partial[(size_t)d * BATCH + b];
  out[b] = s;
}

extern "C" void kernel_launch(void* const* d_in, const int* in_sizes, int n_in,
                              void* d_out, int out_size, void* d_ws, size_t ws_size,
                              hipStream_t stream) {
  const float* x = (const float*)d_in[0];
  const float* W[7];
  const float* B[7];
  for (int l = 0; l < 7; ++l) {
    W[l] = (const float*)d_in[1 + 2 * l];
    B[l] = (const float*)d_in[2 + 2 * l];
  }
  float* partial = (float*)d_ws;  // 2 MB

  mlp_fused<<<dim3(DIM, 2), dim3(512), 0, stream>>>(
      x, W[0], B[0], W[1], B[1], W[2], B[2], W[3], B[3], W[4], B[4], W[5], B[5],
      W[6], B[6], partial);

  reduce_kernel<<<dim3(BATCH / 256), dim3(256), 0, stream>>>(partial,
                                                             (float*)d_out);
}